// Round 2
// baseline (511.791 us; speedup 1.0000x reference)
//
#include <hip/hip_runtime.h>

#define T_SEQ 512
#define ISZ 8
#define HID 64
#define L2E 1.44269504088896340736f

typedef __bf16 bf16x8 __attribute__((ext_vector_type(8)));
typedef float  f32x4  __attribute__((ext_vector_type(4)));

__device__ __forceinline__ float exp2_hw(float x) {
    float r; asm("v_exp_f32 %0, %1" : "=v"(r) : "v"(x)); return r;
}
__device__ __forceinline__ unsigned cvt_pk_bf16(float a, float b) {
    unsigned r; asm("v_cvt_pk_bf16_f32 %0, %1, %2" : "=v"(r) : "v"(a), "v"(b)); return r;
}

// v9: 1024 blocks x 4 batch rows, 4 waves; wave w owns j-slice [16w,16w+16).
// M half-packed split precision: A row 4k = bf16-hi of batch row k, 4k+1 = lo
// residual, 4k+2/3 = zero. Same 12 MFMAs/wave/step as v7 (MFMA pipe had 72%
// headroom) but 2x waves/SIMD (4 blocks/CU) and HALF the per-lane activation
// chain (1 cell/lane). v8 post-mortem: in-wave ILP cannot cover a barrier;
// waves/SIMD is load-bearing -> raise TLP, not ILP.
__global__ __launch_bounds__(256, 4) void lstm_v9_kernel(
    const float* __restrict__ x,
    const float* __restrict__ W_ih,
    const float* __restrict__ W_hh,
    const float* __restrict__ b_ih,
    const float* __restrict__ b_hh,
    const float* __restrict__ W_dense,
    const float* __restrict__ b_dense,
    float* __restrict__ out)
{
    __shared__ __align__(16) __bf16 hpl[2][16 * 64];  // h planes: row 4k hi, 4k+1 lo, 4k+2/3 zero
    __shared__ __align__(16) __bf16 xs[2][80];        // x strip: [plane][hi 0:31 | lo 32:63 | pad]
    __shared__ __align__(16) __bf16 xz[8];            // zero frag

    const int tid  = threadIdx.x;
    const int lane = tid & 63;
    const int w    = tid >> 6;
    const int q    = lane >> 4;          // k-chunk: k = 32s + 8q + e
    const int sub  = lane & 15;          // A row / B col
    const long b0  = (long)blockIdx.x * 4;

    // ---------------- B fragments: bf16(W * gate-scale) ----------------
    bf16x8 Bg[4][3];
    float biasg[4];
    #pragma unroll
    for (int g = 0; g < 4; ++g) {
        const int m = g * HID + 16 * w + sub;
        const float sc = (g == 2) ? (2.0f * L2E) : (-L2E);
        biasg[g] = (b_ih[m] + b_hh[m]) * sc;
        #pragma unroll
        for (int s = 0; s < 3; ++s) {
            #pragma unroll
            for (int e = 0; e < 8; ++e) {
                const int k = 32 * s + 8 * q + e;
                float v = 0.0f;
                if (k < HID)            v = W_hh[m * HID + k] * sc;
                else if (k < HID + ISZ) v = W_ih[m * ISZ + (k - HID)] * sc;
                Bg[g][s][e] = (__bf16)v;
            }
        }
    }
    // bias seeded into MFMA C-input: hi row (reg 0) gets bias, others 0
    f32x4 Cs[4];
    #pragma unroll
    for (int g = 0; g < 4; ++g) { Cs[g][0] = biasg[g]; Cs[g][1] = 0.f; Cs[g][2] = 0.f; Cs[g][3] = 0.f; }

    // dense weights: col 0 = hi, col 1 = lo residual
    bf16x8 Bwd[2];
    #pragma unroll
    for (int s = 0; s < 2; ++s) {
        #pragma unroll
        for (int e = 0; e < 8; ++e) {
            const int k = 32 * s + 8 * q + e;
            const float wv = W_dense[k];
            const __bf16 whi = (__bf16)wv;
            float val = (sub == 0) ? (float)whi : (sub == 1) ? (wv - (float)whi) : 0.0f;
            Bwd[s][e] = (__bf16)val;
        }
    }

    // zero BOTH h planes (plane1 = h(-1); rows 4k+2/3 must stay zero forever)
    for (int i = tid; i < 1024; i += 256) ((float*)&hpl[0][0])[i] = 0.0f;
    if (tid < 4) ((float*)&xz[0])[tid] = 0.0f;

    // ---------------- x producer (wave 3, lanes 0-7) ----------------
    const int  pr = lane >> 1, ph = lane & 1;               // row 0-3, float4-half
    const float* xbase = x + ((b0 + pr) * (long)T_SEQ) * ISZ + ph * 4;
    const int  xoffH = pr * 8 + ph * 4;                     // strip element offsets
    const int  xoffL = 32 + xoffH;

#define XWRITE(XV, DST)                                                      \
    {                                                                        \
        unsigned h01 = cvt_pk_bf16(XV.x, XV.y);                              \
        unsigned h23 = cvt_pk_bf16(XV.z, XV.w);                              \
        float f0 = __uint_as_float(h01 << 16);                               \
        float f1 = __uint_as_float(h01 & 0xffff0000u);                       \
        float f2 = __uint_as_float(h23 << 16);                               \
        float f3 = __uint_as_float(h23 & 0xffff0000u);                       \
        unsigned l01 = cvt_pk_bf16(XV.x - f0, XV.y - f1);                    \
        unsigned l23 = cvt_pk_bf16(XV.z - f2, XV.w - f3);                    \
        uint2 hh2; hh2.x = h01; hh2.y = h23;                                 \
        uint2 ll2; ll2.x = l01; ll2.y = l23;                                 \
        *(uint2*)&(DST)[xoffH] = hh2;                                        \
        *(uint2*)&(DST)[xoffL] = ll2;                                        \
    }

    if (w == 3 && lane < 8) { float4 xv = *(const float4*)xbase; XWRITE(xv, &xs[0][0]) }

    // consumer x-frag pointers (invariant; one per plane).
    // A-row sub content: (sub&2) ? zero : (sub&1 ? lo : hi) of batch row sub>>2.
    const bool xvalid = (q == 0) && !(sub & 2);
    const int  xoff   = ((sub & 1) ? 32 : 0) + (sub >> 2) * 8;
    const __bf16* xrd0 = xvalid ? &xs[0][xoff] : &xz[0];
    const __bf16* xrd1 = xvalid ? &xs[1][xoff] : &xz[0];

    // ---------------- state ----------------
    float c0 = 0.f;                      // c for this lane's cell (batch row q)
    const float bd  = b_dense[0];
    const f32x4 Z   = {0.f, 0.f, 0.f, 0.f};
    const int  swz  = (sub & 7) << 3;
    const int  jme  = 16 * w + sub;

    float s0[4];                         // rolling 4-step dense outputs (w0, sub==0 lanes)
    s0[0]=s0[1]=s0[2]=s0[3]=0.f;

    __syncthreads();

#define MF(A, B, C) __builtin_amdgcn_mfma_f32_16x16x32_bf16(A, B, C, 0, 0, 0)

    // P = unroll pos, PB = h plane holding h(t-1), XR = this step's x-frag ptr,
    // XW = strip plane to write x(t+1) into (all compile-time per macro site).
#define STEP(P, PB, XR, XW)                                                          \
    {                                                                                \
        const int t = tb + P;                                                        \
        /* producer: issue next x load early (consumed at step bottom) */            \
        float4 xv;                                                                   \
        if (w == 3 && lane < 8) {                                                    \
            const int tn = (t + 1 < T_SEQ) ? (t + 1) : (T_SEQ - 1);                  \
            xv = *(const float4*)(xbase + (long)tn * ISZ);                           \
        }                                                                            \
        /* A rebuild: x frag (1 read) + h frags (2 reads), invariant addresses */    \
        bf16x8 Ax  = *(const bf16x8*)(XR);                                           \
        bf16x8 Ah0 = *(const bf16x8*)&hpl[PB][sub * 64 + ((8 * q)      ^ swz)];      \
        bf16x8 Ah1 = *(const bf16x8*)&hpl[PB][sub * 64 + ((32 + 8 * q) ^ swz)];      \
        /* 12 gate MFMAs, bias pre-seeded in C */                                    \
        __builtin_amdgcn_s_setprio(1);                                               \
        f32x4 a0 = MF(Ax, Bg[0][2], Cs[0]);                                          \
        f32x4 a1 = MF(Ax, Bg[1][2], Cs[1]);                                          \
        f32x4 a2 = MF(Ax, Bg[2][2], Cs[2]);                                          \
        f32x4 a3 = MF(Ax, Bg[3][2], Cs[3]);                                          \
        a0 = MF(Ah0, Bg[0][0], a0); a0 = MF(Ah1, Bg[0][1], a0);                      \
        a1 = MF(Ah0, Bg[1][0], a1); a1 = MF(Ah1, Bg[1][1], a1);                      \
        a2 = MF(Ah0, Bg[2][0], a2); a2 = MF(Ah1, Bg[2][1], a2);                      \
        a3 = MF(Ah0, Bg[3][0], a3); a3 = MF(Ah1, Bg[3][1], a3);                      \
        __builtin_amdgcn_s_setprio(0);                                               \
        /* dense o(t-1) on wave 0 (off the critical path) */                         \
        if (w == 0) {                                                                \
            f32x4 oz = MF(Ah0, Bwd[0], Z);                                           \
            oz = MF(Ah1, Bwd[1], oz);                                                \
            float v0 = oz[0] + oz[1];                                                \
            v0 += __shfl_xor(v0, 1);                                                 \
            s0[(P + 3) & 3] = v0;                                                    \
        }                                                                            \
        /* intra-lane hi+lo merge + fused-rcp activations: 1 cell/lane */            \
        {                                                                            \
            const float gi = a0[0] + a0[1];                                          \
            const float gf = a1[0] + a1[1];                                          \
            const float gg = a2[0] + a2[1];                                          \
            const float go = a3[0] + a3[1];                                          \
            const float eA = exp2_hw(gi);                                            \
            const float eF = exp2_hw(gf);                                            \
            const float eB = exp2_hw(gg);                                            \
            const float ig = (eB - 1.0f) *                                           \
                __builtin_amdgcn_rcpf((1.0f + eA) * (1.0f + eB));                    \
            const float ff = __builtin_amdgcn_rcpf(1.0f + eF);                       \
            c0 = fmaf(ff, c0, ig);                                                   \
            const float eO = exp2_hw(go);                                            \
            const float eC = exp2_hw(fminf(c0 * (2.0f * L2E), 80.0f));               \
            const float hh = (eC - 1.0f) *                                           \
                __builtin_amdgcn_rcpf((1.0f + eO) * (1.0f + eC));                    \
            const __bf16 hi = (__bf16)hh;                                            \
            const __bf16 lo = (__bf16)(hh - (float)hi);                              \
            const int rh = 4 * q;                                                    \
            const int rl = rh + 1;                                                   \
            hpl[PB ^ 1][rh * 64 + (jme ^ ((rh & 7) << 3))] = hi;                     \
            hpl[PB ^ 1][rl * 64 + (jme ^ ((rl & 7) << 3))] = lo;                     \
        }                                                                            \
        /* producer: convert + write x(t+1) strip (load latency now hidden) */       \
        if (w == 3 && lane < 8) XWRITE(xv, &xs[XW][0])                               \
        /* batched coalesced store: window [tb-4, tb-1], once per 4 steps */         \
        if (P == 0) {                                                                \
            if (w == 0 && sub == 0 && tb >= 4) {                                     \
                *(float4*)&out[(b0 + q) * T_SEQ + tb - 4] =                          \
                    make_float4(s0[0] + bd, s0[1] + bd, s0[2] + bd, s0[3] + bd);     \
            }                                                                        \
        }                                                                            \
        /* raw barrier: LDS-only drain; vmcnt (x loads + out stores) in flight */    \
        asm volatile("s_waitcnt lgkmcnt(0)" ::: "memory");                           \
        __builtin_amdgcn_s_barrier();                                                \
        __builtin_amdgcn_sched_barrier(0);                                           \
    }

    for (int tb = 0; tb < T_SEQ; tb += 4) {
        STEP(0, 1, xrd0, 1)
        STEP(1, 0, xrd1, 0)
        STEP(2, 1, xrd0, 1)
        STEP(3, 0, xrd1, 0)
    }
#undef STEP

    // ---- epilogue: o(511) from h(511) (plane 1); store window [508, 511] ----
    if (w == 0) {
        bf16x8 Eh0 = *(const bf16x8*)&hpl[1][sub * 64 + ((8 * q)      ^ swz)];
        bf16x8 Eh1 = *(const bf16x8*)&hpl[1][sub * 64 + ((32 + 8 * q) ^ swz)];
        f32x4 oz = MF(Eh0, Bwd[0], Z);
        oz = MF(Eh1, Bwd[1], oz);
        float v0 = oz[0] + oz[1];
        v0 += __shfl_xor(v0, 1);
        s0[3] = v0;
        if (sub == 0) {
            *(float4*)&out[(b0 + q) * T_SEQ + (T_SEQ - 4)] =
                make_float4(s0[0] + bd, s0[1] + bd, s0[2] + bd, s0[3] + bd);
        }
    }
#undef MF
#undef XWRITE
}

extern "C" void kernel_launch(void* const* d_in, const int* in_sizes, int n_in,
                              void* d_out, int out_size, void* d_ws, size_t ws_size,
                              hipStream_t stream) {
    const float* x       = (const float*)d_in[0];
    const float* W_ih    = (const float*)d_in[1];
    const float* W_hh    = (const float*)d_in[2];
    const float* b_ih    = (const float*)d_in[3];
    const float* b_hh    = (const float*)d_in[4];
    const float* W_dense = (const float*)d_in[5];
    const float* b_dense = (const float*)d_in[6];
    float* out = (float*)d_out;

    const int B = in_sizes[0] / (T_SEQ * ISZ);   // 4096
    const int blocks = B / 4;                     // 1024 blocks -> 4 blocks/CU, 4 waves/SIMD
    lstm_v9_kernel<<<blocks, 256, 0, stream>>>(x, W_ih, W_hh, b_ih, b_hh,
                                               W_dense, b_dense, out);
}

// Round 3
// 275.333 us; speedup vs baseline: 1.8588x; 1.8588x over previous
//
#include <hip/hip_runtime.h>

#define T_SEQ 512
#define ISZ 8
#define HID 64
#define L2E 1.44269504088896340736f

typedef __bf16 bf16x8 __attribute__((ext_vector_type(8)));
typedef float  f32x4  __attribute__((ext_vector_type(4)));

__device__ __forceinline__ float exp2_hw(float x) {
    float r; asm("v_exp_f32 %0, %1" : "=v"(r) : "v"(x)); return r;
}
__device__ __forceinline__ unsigned cvt_pk_bf16(float a, float b) {
    unsigned r; asm("v_cvt_pk_bf16_f32 %0, %1, %2" : "=v"(r) : "v"(a), "v"(b)); return r;
}

// v10 = v7 (the verified 281us structure: 512 blocks x 8 rows, 4 waves,
// M-packed hi/lo split precision, XOR-swizzled h planes, bias-seeded C,
// fused-rcp activations, raw barrier w/ lgkmcnt-only drain) + ONE change:
// depth-4 x register pipeline on the producer wave. v7 loaded x(t+1) at
// step top and consumed it at step bottom (~500cyc gap < L3/HBM latency;
// FETCH=33MB of 64MB x says ~half the stream misses L2). w3's vmcnt stall
// gates the barrier for all 8 waves/CU. Now: strip write (from a register
// loaded 4 steps ago, ~2600cyc cover) happens at step TOP overlapped with
// MFMAs, and the refill load for t+5 is issued right after.
// v8/v9 lesson: 650cyc/block-step is invariant to occupancy changes; only
// in-step work/latency removal helps. Structure must stay exactly v7.
__global__ __launch_bounds__(256, 2) void lstm_v10_kernel(
    const float* __restrict__ x,
    const float* __restrict__ W_ih,
    const float* __restrict__ W_hh,
    const float* __restrict__ b_ih,
    const float* __restrict__ b_hh,
    const float* __restrict__ W_dense,
    const float* __restrict__ b_dense,
    float* __restrict__ out)
{
    __shared__ __align__(16) __bf16 hpl[2][16 * 64];  // h planes: hi rows {4k,4k+1}, lo {4k+2,4k+3}
    __shared__ __align__(16) __bf16 xs[2][160];       // x strip: [plane][hi 0:63 | lo 64:127 | pad]
    __shared__ __align__(16) __bf16 xz[8];            // zero frag (q!=0 lanes)

    const int tid  = threadIdx.x;
    const int lane = tid & 63;
    const int w    = tid >> 6;
    const int q    = lane >> 4;          // k-chunk: k = 32s + 8q + e
    const int sub  = lane & 15;          // A row / B col
    const int br   = 2 * (sub >> 2) + (sub & 1);   // batch row carried by A-row sub
    const bool isLo = (sub & 2) != 0;
    const long b0  = (long)blockIdx.x * 8;

    // ---------------- B fragments: bf16(W * gate-scale) ----------------
    bf16x8 Bg[4][3];
    float biasg[4];
    #pragma unroll
    for (int g = 0; g < 4; ++g) {
        const int m = g * HID + 16 * w + sub;
        const float sc = (g == 2) ? (2.0f * L2E) : (-L2E);
        biasg[g] = (b_ih[m] + b_hh[m]) * sc;
        #pragma unroll
        for (int s = 0; s < 3; ++s) {
            #pragma unroll
            for (int e = 0; e < 8; ++e) {
                const int k = 32 * s + 8 * q + e;
                float v = 0.0f;
                if (k < HID)            v = W_hh[m * HID + k] * sc;
                else if (k < HID + ISZ) v = W_ih[m * ISZ + (k - HID)] * sc;
                Bg[g][s][e] = (__bf16)v;
            }
        }
    }
    // bias seeded into MFMA C-input: hi rows get bias, lo rows 0
    f32x4 Cs[4];
    #pragma unroll
    for (int g = 0; g < 4; ++g) { Cs[g][0] = biasg[g]; Cs[g][1] = biasg[g]; Cs[g][2] = 0.f; Cs[g][3] = 0.f; }

    // dense weights: col 0 = hi, col 1 = lo residual
    bf16x8 Bwd[2];
    #pragma unroll
    for (int s = 0; s < 2; ++s) {
        #pragma unroll
        for (int e = 0; e < 8; ++e) {
            const int k = 32 * s + 8 * q + e;
            const float wv = W_dense[k];
            const __bf16 whi = (__bf16)wv;
            float val = (sub == 0) ? (float)whi : (sub == 1) ? (wv - (float)whi) : 0.0f;
            Bwd[s][e] = (__bf16)val;
        }
    }

    // zero h plane 1 (= h(-1)) and the zero x-frag
    for (int i = tid; i < 512; i += 256) ((float*)&hpl[1][0])[i] = 0.0f;
    if (tid < 4) ((float*)&xz[0])[tid] = 0.0f;

    // ---------------- x producer (wave 3, lanes 0-15) ----------------
    const int  pr = lane >> 1, ph = lane & 1;               // row 0-7, float4-half
    const float* xbase = x + ((b0 + pr) * (long)T_SEQ) * ISZ + ph * 4;
    const int  xoffH = pr * 8 + ph * 4;                     // strip element offsets
    const int  xoffL = 64 + xoffH;

#define XWRITE(XV, DST)                                                      \
    {                                                                        \
        unsigned h01 = cvt_pk_bf16(XV.x, XV.y);                              \
        unsigned h23 = cvt_pk_bf16(XV.z, XV.w);                              \
        float f0 = __uint_as_float(h01 << 16);                               \
        float f1 = __uint_as_float(h01 & 0xffff0000u);                       \
        float f2 = __uint_as_float(h23 << 16);                               \
        float f3 = __uint_as_float(h23 & 0xffff0000u);                       \
        unsigned l01 = cvt_pk_bf16(XV.x - f0, XV.y - f1);                    \
        unsigned l23 = cvt_pk_bf16(XV.z - f2, XV.w - f3);                    \
        uint2 hh2; hh2.x = h01; hh2.y = h23;                                 \
        uint2 ll2; ll2.x = l01; ll2.y = l23;                                 \
        *(uint2*)&(DST)[xoffH] = hh2;                                        \
        *(uint2*)&(DST)[xoffL] = ll2;                                        \
    }

    // depth-4 x register pipeline (producer lanes only)
    float4 xp0, xp1, xp2, xp3;
    if (w == 3 && lane < 16) {
        float4 xv0 = *(const float4*)xbase;                 // x(0) -> strip plane 0
        XWRITE(xv0, &xs[0][0])
        xp1 = *(const float4*)(xbase + (long)1 * ISZ);      // x(1)
        xp2 = *(const float4*)(xbase + (long)2 * ISZ);      // x(2)
        xp3 = *(const float4*)(xbase + (long)3 * ISZ);      // x(3)
        xp0 = *(const float4*)(xbase + (long)4 * ISZ);      // x(4)
    }

    // consumer x-frag pointers (invariant; one per plane)
    const __bf16* xrd0 = (q == 0) ? &xs[0][(isLo ? 64 : 0) + br * 8] : &xz[0];
    const __bf16* xrd1 = (q == 0) ? &xs[1][(isLo ? 64 : 0) + br * 8] : &xz[0];

    // ---------------- state ----------------
    float c0 = 0.f, c1 = 0.f;            // c for this lane's cells (rows 2q, 2q+1)
    const float bd  = b_dense[0];
    const f32x4 Z   = {0.f, 0.f, 0.f, 0.f};
    const int  swz  = (sub & 7) << 3;
    const int  jme  = 16 * w + sub;

    float s0[4], s1[4];                  // rolling 4-step dense outputs (w0 lanes)
    s0[0]=s0[1]=s0[2]=s0[3]=0.f;
    s1[0]=s1[1]=s1[2]=s1[3]=0.f;

    __syncthreads();

#define MF(A, B, C) __builtin_amdgcn_mfma_f32_16x16x32_bf16(A, B, C, 0, 0, 0)

    // P = unroll pos, PB = h plane holding h(t-1), XR = this step's x-frag ptr,
    // XW = strip plane to write x(t+1) into, XP = pipeline reg holding x(t+1)
    // (loaded 4 steps ago; refilled here with x(t+5)).
#define STEP(P, PB, XR, XW, XP)                                                      \
    {                                                                                \
        const int t = tb + P;                                                        \
        /* producer: strip write from 4-step-old reg (latency fully covered), */     \
        /* overlapped with the MFMA phase; then refill the slot with x(t+5). */      \
        if (w == 3 && lane < 16) {                                                   \
            XWRITE(XP, &xs[XW][0])                                                   \
            const int tn = (t + 5 < T_SEQ) ? (t + 5) : (T_SEQ - 1);                  \
            XP = *(const float4*)(xbase + (long)tn * ISZ);                           \
        }                                                                            \
        /* A rebuild: x frag (1 read) + h frags (2 reads), invariant addresses */    \
        bf16x8 Ax  = *(const bf16x8*)(XR);                                           \
        bf16x8 Ah0 = *(const bf16x8*)&hpl[PB][sub * 64 + ((8 * q)      ^ swz)];      \
        bf16x8 Ah1 = *(const bf16x8*)&hpl[PB][sub * 64 + ((32 + 8 * q) ^ swz)];      \
        /* 12 gate MFMAs, bias pre-seeded in C */                                    \
        __builtin_amdgcn_s_setprio(1);                                               \
        f32x4 a0 = MF(Ax, Bg[0][2], Cs[0]);                                          \
        f32x4 a1 = MF(Ax, Bg[1][2], Cs[1]);                                          \
        f32x4 a2 = MF(Ax, Bg[2][2], Cs[2]);                                          \
        f32x4 a3 = MF(Ax, Bg[3][2], Cs[3]);                                          \
        a0 = MF(Ah0, Bg[0][0], a0); a0 = MF(Ah1, Bg[0][1], a0);                      \
        a1 = MF(Ah0, Bg[1][0], a1); a1 = MF(Ah1, Bg[1][1], a1);                      \
        a2 = MF(Ah0, Bg[2][0], a2); a2 = MF(Ah1, Bg[2][1], a2);                      \
        a3 = MF(Ah0, Bg[3][0], a3); a3 = MF(Ah1, Bg[3][1], a3);                      \
        __builtin_amdgcn_s_setprio(0);                                               \
        /* dense o(t-1) on wave 0 (off the critical path) */                         \
        if (w == 0) {                                                                \
            f32x4 oz = MF(Ah0, Bwd[0], Z);                                           \
            oz = MF(Ah1, Bwd[1], oz);                                                \
            float v0 = oz[0] + oz[2];                                                \
            float v1 = oz[1] + oz[3];                                                \
            v0 += __shfl_xor(v0, 1);                                                 \
            v1 += __shfl_xor(v1, 1);                                                 \
            s0[(P + 3) & 3] = v0;                                                    \
            s1[(P + 3) & 3] = v1;                                                    \
        }                                                                            \
        /* intra-lane hi+lo merge + fused-rcp activations: 2 cells/lane */           \
        _Pragma("unroll")                                                            \
        for (int i = 0; i < 2; ++i) {                                                \
            const float gi = a0[i] + a0[2 + i];                                      \
            const float gf = a1[i] + a1[2 + i];                                      \
            const float gg = a2[i] + a2[2 + i];                                      \
            const float go = a3[i] + a3[2 + i];                                      \
            const float eA = exp2_hw(gi);                                            \
            const float eF = exp2_hw(gf);                                            \
            const float eB = exp2_hw(gg);                                            \
            const float ig = (eB - 1.0f) *                                           \
                __builtin_amdgcn_rcpf((1.0f + eA) * (1.0f + eB));                    \
            const float ff = __builtin_amdgcn_rcpf(1.0f + eF);                       \
            float cc = i ? c1 : c0;                                                  \
            cc = fmaf(ff, cc, ig);                                                   \
            if (i) c1 = cc; else c0 = cc;                                            \
            const float eO = exp2_hw(go);                                            \
            const float eC = exp2_hw(fminf(cc * (2.0f * L2E), 80.0f));               \
            const float hh = (eC - 1.0f) *                                           \
                __builtin_amdgcn_rcpf((1.0f + eO) * (1.0f + eC));                    \
            const __bf16 hi = (__bf16)hh;                                            \
            const __bf16 lo = (__bf16)(hh - (float)hi);                              \
            const int rh = 4 * q + i;                                                \
            const int rl = rh + 2;                                                   \
            hpl[PB ^ 1][rh * 64 + (jme ^ ((rh & 7) << 3))] = hi;                     \
            hpl[PB ^ 1][rl * 64 + (jme ^ ((rl & 7) << 3))] = lo;                     \
        }                                                                            \
        /* batched coalesced store: window [tb-4, tb-1], once per 4 steps */         \
        if (P == 0) {                                                                \
            if (w == 0 && sub == 0 && tb >= 4) {                                     \
                *(float4*)&out[(b0 + 2 * q) * T_SEQ + tb - 4] =                      \
                    make_float4(s0[0] + bd, s0[1] + bd, s0[2] + bd, s0[3] + bd);     \
                *(float4*)&out[(b0 + 2 * q + 1) * T_SEQ + tb - 4] =                  \
                    make_float4(s1[0] + bd, s1[1] + bd, s1[2] + bd, s1[3] + bd);     \
            }                                                                        \
        }                                                                            \
        /* raw barrier: LDS-only drain; vmcnt (x loads + out stores) in flight */    \
        asm volatile("s_waitcnt lgkmcnt(0)" ::: "memory");                           \
        __builtin_amdgcn_s_barrier();                                                \
        __builtin_amdgcn_sched_barrier(0);                                           \
    }

    for (int tb = 0; tb < T_SEQ; tb += 4) {
        STEP(0, 1, xrd0, 1, xp1)
        STEP(1, 0, xrd1, 0, xp2)
        STEP(2, 1, xrd0, 1, xp3)
        STEP(3, 0, xrd1, 0, xp0)
    }
#undef STEP

    // ---- epilogue: o(511) from h(511) (plane 1); store window [508, 511] ----
    if (w == 0) {
        bf16x8 Eh0 = *(const bf16x8*)&hpl[1][sub * 64 + ((8 * q)      ^ swz)];
        bf16x8 Eh1 = *(const bf16x8*)&hpl[1][sub * 64 + ((32 + 8 * q) ^ swz)];
        f32x4 oz = MF(Eh0, Bwd[0], Z);
        oz = MF(Eh1, Bwd[1], oz);
        float v0 = oz[0] + oz[2];
        float v1 = oz[1] + oz[3];
        v0 += __shfl_xor(v0, 1);
        v1 += __shfl_xor(v1, 1);
        s0[3] = v0;
        s1[3] = v1;
        if (sub == 0) {
            *(float4*)&out[(b0 + 2 * q) * T_SEQ + (T_SEQ - 4)] =
                make_float4(s0[0] + bd, s0[1] + bd, s0[2] + bd, s0[3] + bd);
            *(float4*)&out[(b0 + 2 * q + 1) * T_SEQ + (T_SEQ - 4)] =
                make_float4(s1[0] + bd, s1[1] + bd, s1[2] + bd, s1[3] + bd);
        }
    }
#undef MF
#undef XWRITE
}

extern "C" void kernel_launch(void* const* d_in, const int* in_sizes, int n_in,
                              void* d_out, int out_size, void* d_ws, size_t ws_size,
                              hipStream_t stream) {
    const float* x       = (const float*)d_in[0];
    const float* W_ih    = (const float*)d_in[1];
    const float* W_hh    = (const float*)d_in[2];
    const float* b_ih    = (const float*)d_in[3];
    const float* b_hh    = (const float*)d_in[4];
    const float* W_dense = (const float*)d_in[5];
    const float* b_dense = (const float*)d_in[6];
    float* out = (float*)d_out;

    const int B = in_sizes[0] / (T_SEQ * ISZ);   // 4096
    const int blocks = B / 8;                     // 512 blocks -> 2 blocks/CU
    lstm_v10_kernel<<<blocks, 256, 0, stream>>>(x, W_ih, W_hh, b_ih, b_hh,
                                                W_dense, b_dense, out);
}